// Round 1
// baseline (21129.013 us; speedup 1.0000x reference)
//
#include <hip/hip_runtime.h>
#include <cstdint>
#include <cstddef>

#define NB 4
#define NT 8
#define NC 256
#define NH 64
#define NW 64
#define NDH 128
#define CCH 8            // input channels per LDS chunk
#define XSW 68           // padded stage row width (66 used, 68 for banks)
#define HWs (NH * NW)

// Stage x channels [c0, c0+CCH) rows h-1..h+1 cols -1..64 (zero-padded halo).
// chan points at channel c0 of the frame.
__device__ __forceinline__ void stage_x(const float* __restrict__ chan, int h,
                                        float* __restrict__ sx, int tid) {
    const int total = CCH * 3 * 66;
    for (int e = tid; e < total; e += 256) {
        int cc  = e / 198;            // 3*66
        int rem = e - cc * 198;
        int r   = rem / 66;
        int col = rem - r * 66 - 1;   // -1..64
        int hs  = h - 1 + r;
        float v = 0.0f;
        if ((unsigned)hs < (unsigned)NH && (unsigned)col < (unsigned)NW)
            v = chan[(size_t)cc * HWs + hs * NW + col];
        sx[(cc * 3 + r) * XSW + col + 1] = v;
    }
}

// Stage weights: 128 output channels x CCH input channels x 9 taps.
// wbase = wgt + ((size_t)oc_base*Cin + c0)*9 ; Cin9 = Cin*9.
// sw layout: [oc_local][72] (72 = CCH*9, contiguous per oc -> coalesced loads)
__device__ __forceinline__ void stage_w(const float* __restrict__ wbase, int Cin9,
                                        float* __restrict__ sw, int tid) {
    const int total = 128 * 72;
    for (int e = tid; e < total; e += 256) {
        int oc = e / 72;
        int r  = e - oc * 72;
        sw[e] = wbase[(size_t)oc * Cin9 + r];
    }
}

// Per-thread conv over one channel chunk: accumulates 4 oc x 8 px.
__device__ __forceinline__ void conv_chunk(const float* __restrict__ sx,
                                           const float* __restrict__ sw,
                                           int ocl0, int w0, float acc[4][8]) {
    for (int cc = 0; cc < CCH; ++cc) {
        float xr[3][10];
        #pragma unroll
        for (int r = 0; r < 3; ++r)
            #pragma unroll
            for (int j = 0; j < 10; ++j)
                xr[r][j] = sx[(cc * 3 + r) * XSW + w0 + j];  // col w0-1+j
        #pragma unroll
        for (int i = 0; i < 4; ++i) {
            float wr[9];
            #pragma unroll
            for (int j = 0; j < 9; ++j)
                wr[j] = sw[(ocl0 + i) * 72 + cc * 9 + j];
            #pragma unroll
            for (int ky = 0; ky < 3; ++ky)
                #pragma unroll
                for (int kx = 0; kx < 3; ++kx)
                    #pragma unroll
                    for (int p = 0; p < 8; ++p)
                        acc[i][p] += wr[ky * 3 + kx] * xr[ky][p + kx];
        }
    }
}

// ---------------- K1: k = conv(x[:,0], w_k) ----------------
__global__ __launch_bounds__(256) void conv_k_kernel(const float* __restrict__ x,
        const float* __restrict__ w_k, float* __restrict__ kout) {
    __shared__ float sx[CCH * 3 * XSW];
    __shared__ float sw[128 * 72];
    int blk = blockIdx.x;                 // b*64 + h
    int b = blk >> 6, h = blk & 63;
    int tid = threadIdx.x;
    int dhg = tid & 31, wg = tid >> 5;
    int ocl0 = dhg * 4, w0 = wg * 8;
    const float* frame = x + (size_t)b * NT * NC * HWs;   // t = 0
    float acc[4][8];
    #pragma unroll
    for (int i = 0; i < 4; ++i)
        #pragma unroll
        for (int p = 0; p < 8; ++p) acc[i][p] = 0.0f;
    for (int c0 = 0; c0 < NC; c0 += CCH) {
        __syncthreads();
        stage_x(frame + (size_t)c0 * HWs, h, sx, tid);
        stage_w(w_k + (size_t)c0 * 9, NC * 9, sw, tid);
        __syncthreads();
        conv_chunk(sx, sw, ocl0, w0, acc);
    }
    #pragma unroll
    for (int i = 0; i < 4; ++i)
        #pragma unroll
        for (int p = 0; p < 8; ++p)
            kout[((size_t)b * NDH + ocl0 + i) * HWs + h * NW + w0 + p] = acc[i][p];
}

// ---------------- K2: dots[b,t,h,w] = sum_dh conv_q(x[b,t]) * k ----------------
__global__ __launch_bounds__(256) void conv_q_dots_kernel(const float* __restrict__ x,
        const float* __restrict__ w_q, const float* __restrict__ kbuf,
        float* __restrict__ dots) {
    __shared__ float sx[CCH * 3 * XSW];
    __shared__ float sw[128 * 72];
    int blk = blockIdx.x;                 // (b*NT+t)*64 + h
    int h = blk & 63;
    int bt = blk >> 6;
    int b = bt >> 3;
    int tid = threadIdx.x;
    int dhg = tid & 31, wg = tid >> 5;
    int ocl0 = dhg * 4, w0 = wg * 8;
    const float* frame = x + (size_t)bt * NC * HWs;
    float acc[4][8];
    #pragma unroll
    for (int i = 0; i < 4; ++i)
        #pragma unroll
        for (int p = 0; p < 8; ++p) acc[i][p] = 0.0f;
    for (int c0 = 0; c0 < NC; c0 += CCH) {
        __syncthreads();
        stage_x(frame + (size_t)c0 * HWs, h, sx, tid);
        stage_w(w_q + (size_t)c0 * 9, NC * 9, sw, tid);
        __syncthreads();
        conv_chunk(sx, sw, ocl0, w0, acc);
    }
    float part[8];
    #pragma unroll
    for (int p = 0; p < 8; ++p) part[p] = 0.0f;
    #pragma unroll
    for (int i = 0; i < 4; ++i) {
        const float* kp = kbuf + ((size_t)b * NDH + ocl0 + i) * HWs + h * NW + w0;
        #pragma unroll
        for (int p = 0; p < 8; ++p) part[p] += acc[i][p] * kp[p];
    }
    // reduce over the 32 dh-groups (low 5 lane bits within each half-wave)
    #pragma unroll
    for (int m = 16; m >= 1; m >>= 1)
        #pragma unroll
        for (int p = 0; p < 8; ++p)
            part[p] += __shfl_xor(part[p], m, 64);
    if (dhg == 0) {
        #pragma unroll
        for (int p = 0; p < 8; ++p)
            dots[(size_t)bt * HWs + h * NW + w0 + p] = part[p];
    }
}

// ---------------- K3: softmax over T (in place) ----------------
__global__ __launch_bounds__(256) void softmax_t_kernel(float* __restrict__ dots) {
    int idx = blockIdx.x * 256 + threadIdx.x;   // NB*HWs = 16384 exactly
    int b = idx >> 12;
    int p = idx & 4095;
    float* base = dots + (size_t)b * NT * HWs + p;
    float v[NT];
    float m = -3.4e38f;
    #pragma unroll
    for (int t = 0; t < NT; ++t) { v[t] = base[t * HWs]; m = fmaxf(m, v[t]); }
    float s = 0.0f;
    #pragma unroll
    for (int t = 0; t < NT; ++t) { v[t] = __expf(v[t] - m); s += v[t]; }
    float inv = 1.0f / s;
    #pragma unroll
    for (int t = 0; t < NT; ++t) base[t * HWs] = v[t] * inv;
}

// ---------------- K4: pooled = sum_t attn * conv_v(x[b,t]) ----------------
__global__ __launch_bounds__(256) void conv_v_pool_kernel(const float* __restrict__ x,
        const float* __restrict__ w_v, const float* __restrict__ attn,
        float* __restrict__ pooled) {
    __shared__ float sx[CCH * 3 * XSW];
    __shared__ float sw[128 * 72];
    int blk = blockIdx.x;                 // b*64 + h
    int b = blk >> 6, h = blk & 63;
    int tid = threadIdx.x;
    int dhg = tid & 31, wg = tid >> 5;
    int ocl0 = dhg * 4, w0 = wg * 8;
    float pacc[4][8];
    #pragma unroll
    for (int i = 0; i < 4; ++i)
        #pragma unroll
        for (int p = 0; p < 8; ++p) pacc[i][p] = 0.0f;
    for (int t = 0; t < NT; ++t) {
        const float* frame = x + ((size_t)(b * NT + t)) * NC * HWs;
        float acc[4][8];
        #pragma unroll
        for (int i = 0; i < 4; ++i)
            #pragma unroll
            for (int p = 0; p < 8; ++p) acc[i][p] = 0.0f;
        for (int c0 = 0; c0 < NC; c0 += CCH) {
            __syncthreads();
            stage_x(frame + (size_t)c0 * HWs, h, sx, tid);
            stage_w(w_v + (size_t)c0 * 9, NC * 9, sw, tid);
            __syncthreads();
            conv_chunk(sx, sw, ocl0, w0, acc);
        }
        const float* ap = attn + ((size_t)(b * NT + t)) * HWs + h * NW + w0;
        float a[8];
        #pragma unroll
        for (int p = 0; p < 8; ++p) a[p] = ap[p];
        #pragma unroll
        for (int i = 0; i < 4; ++i)
            #pragma unroll
            for (int p = 0; p < 8; ++p) pacc[i][p] += a[p] * acc[i][p];
    }
    #pragma unroll
    for (int i = 0; i < 4; ++i)
        #pragma unroll
        for (int p = 0; p < 8; ++p)
            pooled[((size_t)b * NDH + ocl0 + i) * HWs + h * NW + w0 + p] = pacc[i][p];
}

// ---------------- K5: out = conv(pooled, w_out) + b_out, broadcast over T ----------------
__global__ __launch_bounds__(256) void conv_out_kernel(const float* __restrict__ pooled,
        const float* __restrict__ w_out, const float* __restrict__ b_out,
        float* __restrict__ out) {
    __shared__ float sx[CCH * 3 * XSW];
    __shared__ float sw[128 * 72];
    int blk = blockIdx.x;                 // ((b*64)+h)*2 + half
    int half = blk & 1;
    int h = (blk >> 1) & 63;
    int b = blk >> 7;
    int tid = threadIdx.x;
    int dhg = tid & 31, wg = tid >> 5;
    int ocl0 = dhg * 4, w0 = wg * 8;
    const float* frame = pooled + (size_t)b * NDH * HWs;
    float acc[4][8];
    #pragma unroll
    for (int i = 0; i < 4; ++i)
        #pragma unroll
        for (int p = 0; p < 8; ++p) acc[i][p] = 0.0f;
    for (int c0 = 0; c0 < NDH; c0 += CCH) {
        __syncthreads();
        stage_x(frame + (size_t)c0 * HWs, h, sx, tid);
        stage_w(w_out + ((size_t)half * 128 * NDH + c0) * 9, NDH * 9, sw, tid);
        __syncthreads();
        conv_chunk(sx, sw, ocl0, w0, acc);
    }
    #pragma unroll
    for (int i = 0; i < 4; ++i) {
        int oc = half * 128 + ocl0 + i;
        float bias = b_out[oc];
        #pragma unroll
        for (int p = 0; p < 8; ++p) {
            float val = acc[i][p] + bias;
            #pragma unroll
            for (int t = 0; t < NT; ++t)
                out[(((size_t)(b * NT + t)) * NC + oc) * HWs + h * NW + w0 + p] = val;
        }
    }
}

extern "C" void kernel_launch(void* const* d_in, const int* in_sizes, int n_in,
                              void* d_out, int out_size, void* d_ws, size_t ws_size,
                              hipStream_t stream) {
    const float* x     = (const float*)d_in[0];
    const float* w_k   = (const float*)d_in[1];
    const float* w_q   = (const float*)d_in[2];
    const float* w_v   = (const float*)d_in[3];
    const float* w_out = (const float*)d_in[4];
    const float* b_out = (const float*)d_in[5];
    float* out = (float*)d_out;

    float* kbuf   = (float*)d_ws;                       // NB*NDH*HWs = 2,097,152 f
    float* dots   = kbuf + (size_t)NB * NDH * HWs;      // NB*NT*HWs  =   131,072 f
    float* pooled = dots + (size_t)NB * NT * HWs;       // NB*NDH*HWs = 2,097,152 f
    // total ws use: ~17.3 MB

    hipLaunchKernelGGL(conv_k_kernel,      dim3(NB * NH),      dim3(256), 0, stream, x, w_k, kbuf);
    hipLaunchKernelGGL(conv_q_dots_kernel, dim3(NB * NT * NH), dim3(256), 0, stream, x, w_q, kbuf, dots);
    hipLaunchKernelGGL(softmax_t_kernel,   dim3(64),           dim3(256), 0, stream, dots);
    hipLaunchKernelGGL(conv_v_pool_kernel, dim3(NB * NH),      dim3(256), 0, stream, x, w_v, dots, pooled);
    hipLaunchKernelGGL(conv_out_kernel,    dim3(NB * NH * 2),  dim3(256), 0, stream, pooled, w_out, b_out, out);
}

// Round 2
// 4776.287 us; speedup vs baseline: 4.4237x; 4.4237x over previous
//
#include <hip/hip_runtime.h>
#include <cstdint>
#include <cstddef>

#define NB 4
#define NT 8
#define NC 256
#define NH 64
#define NW 64
#define NDH 128
#define CCH 8            // input channels per LDS chunk
#define XSW 68           // padded stage row width (66 used; 68 keeps float4 alignment)
#define SWP 73           // per-oc weight stride: 73 -> lane bank stride 9, gcd(9,32)=1, conflict-free
#define HWs (NH * NW)

// Stage x channels [c0, c0+CCH) rows h-1..h+1 cols -1..64 (zero-padded halo).
__device__ __forceinline__ void stage_x(const float* __restrict__ chan, int h,
                                        float* __restrict__ sx, int tid) {
    const int total = CCH * 3 * 66;
    for (int e = tid; e < total; e += 256) {
        int cc  = e / 198;            // 3*66
        int rem = e - cc * 198;
        int r   = rem / 66;
        int col = rem - r * 66 - 1;   // -1..64
        int hs  = h - 1 + r;
        float v = 0.0f;
        if ((unsigned)hs < (unsigned)NH && (unsigned)col < (unsigned)NW)
            v = chan[(size_t)cc * HWs + hs * NW + col];
        sx[(cc * 3 + r) * XSW + col + 1] = v;
    }
}

// Stage weights: OCB output channels x CCH input channels x 9 taps.
// LDS layout: sw[oc*SWP + r], r = cc*9 + tap. Global reads coalesced; LDS writes
// are address-consecutive (+1 skip at oc boundary) -> conflict-free.
template <int OCB>
__device__ __forceinline__ void stage_w(const float* __restrict__ wbase, int Cin9,
                                        float* __restrict__ sw, int tid) {
    const int total = OCB * 72;
    for (int e = tid; e < total; e += 256) {
        int oc = e / 72;
        int r  = e - oc * 72;
        sw[oc * SWP + r] = wbase[(size_t)oc * Cin9 + r];
    }
}

// Per-thread conv over one channel chunk: OCPT oc (oc = dhg + 32*i) x 8 px.
// sx reads: wave-broadcast float4 (free). sw reads: scalar, conflict-free (stride 73).
template <int OCPT>
__device__ __forceinline__ void conv_chunk(const float* __restrict__ sx,
                                           const float* __restrict__ sw,
                                           int dhg, int w0, float acc[OCPT][8]) {
    #pragma unroll
    for (int cc = 0; cc < CCH; ++cc) {
        float xr[3][12];
        #pragma unroll
        for (int r = 0; r < 3; ++r) {
            const float4* rp = (const float4*)(sx + (cc * 3 + r) * XSW + w0);
            float4 a = rp[0], b = rp[1], c = rp[2];
            xr[r][0] = a.x; xr[r][1] = a.y; xr[r][2]  = a.z; xr[r][3]  = a.w;
            xr[r][4] = b.x; xr[r][5] = b.y; xr[r][6]  = b.z; xr[r][7]  = b.w;
            xr[r][8] = c.x; xr[r][9] = c.y; xr[r][10] = c.z; xr[r][11] = c.w;
        }
        #pragma unroll
        for (int i = 0; i < OCPT; ++i) {
            const float* wp = sw + (dhg + 32 * i) * SWP + cc * 9;
            float wr[9];
            #pragma unroll
            for (int j = 0; j < 9; ++j) wr[j] = wp[j];
            #pragma unroll
            for (int ky = 0; ky < 3; ++ky)
                #pragma unroll
                for (int kx = 0; kx < 3; ++kx)
                    #pragma unroll
                    for (int p = 0; p < 8; ++p)
                        acc[i][p] += wr[ky * 3 + kx] * xr[ky][p + kx];
        }
    }
}

// ---------------- K1: k = conv(x[:,0], w_k), 64 oc per block ----------------
__global__ __launch_bounds__(256) void conv_k_kernel(const float* __restrict__ x,
        const float* __restrict__ w_k, float* __restrict__ kout) {
    __shared__ float sx[CCH * 3 * XSW];
    __shared__ float sw[64 * SWP];
    int blk = blockIdx.x;                 // ((b*64)+h)*2 + half
    int half = blk & 1;
    int h = (blk >> 1) & 63;
    int b = blk >> 7;
    int tid = threadIdx.x;
    int dhg = tid & 31, wg = tid >> 5;
    int w0 = wg * 8;
    const float* frame = x + (size_t)b * NT * NC * HWs;   // t = 0
    float acc[2][8];
    #pragma unroll
    for (int i = 0; i < 2; ++i)
        #pragma unroll
        for (int p = 0; p < 8; ++p) acc[i][p] = 0.0f;
    for (int c0 = 0; c0 < NC; c0 += CCH) {
        __syncthreads();
        stage_x(frame + (size_t)c0 * HWs, h, sx, tid);
        stage_w<64>(w_k + ((size_t)(half * 64) * NC + c0) * 9, NC * 9, sw, tid);
        __syncthreads();
        conv_chunk<2>(sx, sw, dhg, w0, acc);
    }
    #pragma unroll
    for (int i = 0; i < 2; ++i) {
        int oc = half * 64 + dhg + 32 * i;
        #pragma unroll
        for (int p = 0; p < 8; ++p)
            kout[((size_t)b * NDH + oc) * HWs + h * NW + w0 + p] = acc[i][p];
    }
}

// ---------------- K2: dots[b,t,h,w] = sum_dh conv_q(x[b,t]) * k ----------------
__global__ __launch_bounds__(256) void conv_q_dots_kernel(const float* __restrict__ x,
        const float* __restrict__ w_q, const float* __restrict__ kbuf,
        float* __restrict__ dots) {
    __shared__ float sx[CCH * 3 * XSW];
    __shared__ float sw[128 * SWP];
    int blk = blockIdx.x;                 // (b*NT+t)*64 + h
    int h = blk & 63;
    int bt = blk >> 6;
    int b = bt >> 3;
    int tid = threadIdx.x;
    int dhg = tid & 31, wg = tid >> 5;
    int w0 = wg * 8;
    const float* frame = x + (size_t)bt * NC * HWs;
    float acc[4][8];
    #pragma unroll
    for (int i = 0; i < 4; ++i)
        #pragma unroll
        for (int p = 0; p < 8; ++p) acc[i][p] = 0.0f;
    for (int c0 = 0; c0 < NC; c0 += CCH) {
        __syncthreads();
        stage_x(frame + (size_t)c0 * HWs, h, sx, tid);
        stage_w<128>(w_q + (size_t)c0 * 9, NC * 9, sw, tid);
        __syncthreads();
        conv_chunk<4>(sx, sw, dhg, w0, acc);
    }
    float part[8];
    #pragma unroll
    for (int p = 0; p < 8; ++p) part[p] = 0.0f;
    #pragma unroll
    for (int i = 0; i < 4; ++i) {
        const float* kp = kbuf + ((size_t)b * NDH + dhg + 32 * i) * HWs + h * NW + w0;
        #pragma unroll
        for (int p = 0; p < 8; ++p) part[p] += acc[i][p] * kp[p];
    }
    // reduce over the 32 dh-groups (low 5 lane bits within each half-wave)
    #pragma unroll
    for (int m = 16; m >= 1; m >>= 1)
        #pragma unroll
        for (int p = 0; p < 8; ++p)
            part[p] += __shfl_xor(part[p], m, 64);
    if (dhg == 0) {
        #pragma unroll
        for (int p = 0; p < 8; ++p)
            dots[(size_t)bt * HWs + h * NW + w0 + p] = part[p];
    }
}

// ---------------- K3: softmax over T (in place) ----------------
__global__ __launch_bounds__(256) void softmax_t_kernel(float* __restrict__ dots) {
    int idx = blockIdx.x * 256 + threadIdx.x;   // NB*HWs = 16384 exactly
    int b = idx >> 12;
    int p = idx & 4095;
    float* base = dots + (size_t)b * NT * HWs + p;
    float v[NT];
    float m = -3.4e38f;
    #pragma unroll
    for (int t = 0; t < NT; ++t) { v[t] = base[t * HWs]; m = fmaxf(m, v[t]); }
    float s = 0.0f;
    #pragma unroll
    for (int t = 0; t < NT; ++t) { v[t] = __expf(v[t] - m); s += v[t]; }
    float inv = 1.0f / s;
    #pragma unroll
    for (int t = 0; t < NT; ++t) base[t * HWs] = v[t] * inv;
}

// ---------------- K4: pooled = sum_t attn * conv_v(x[b,t]), 64 oc per block ------
// Loop order: c0 outer (weights staged once per chunk), t inner (x staged per t),
// exploiting linearity: pooled = sum_c sum_t a_t * conv_chunk_c(x_t).
__global__ __launch_bounds__(256) void conv_v_pool_kernel(const float* __restrict__ x,
        const float* __restrict__ w_v, const float* __restrict__ attn,
        float* __restrict__ pooled) {
    __shared__ float sx[CCH * 3 * XSW];
    __shared__ float sw[64 * SWP];
    __shared__ float sa[NT * NW];
    int blk = blockIdx.x;                 // ((b*64)+h)*2 + half
    int half = blk & 1;
    int h = (blk >> 1) & 63;
    int b = blk >> 7;
    int tid = threadIdx.x;
    int dhg = tid & 31, wg = tid >> 5;
    int w0 = wg * 8;
    // stage attn for (b, all t, row h)
    for (int e = tid; e < NT * NW; e += 256) {
        int t = e >> 6, col = e & 63;
        sa[e] = attn[((size_t)(b * NT + t)) * HWs + h * NW + col];
    }
    float pacc[2][8];
    #pragma unroll
    for (int i = 0; i < 2; ++i)
        #pragma unroll
        for (int p = 0; p < 8; ++p) pacc[i][p] = 0.0f;
    for (int c0 = 0; c0 < NC; c0 += CCH) {
        __syncthreads();   // protect sw/sx (and first-iter sa) from prior reads
        stage_w<64>(w_v + ((size_t)(half * 64) * NC + c0) * 9, NC * 9, sw, tid);
        for (int t = 0; t < NT; ++t) {
            if (t) __syncthreads();
            stage_x(x + ((size_t)(b * NT + t) * NC + c0) * HWs, h, sx, tid);
            __syncthreads();
            float acc[2][8];
            #pragma unroll
            for (int i = 0; i < 2; ++i)
                #pragma unroll
                for (int p = 0; p < 8; ++p) acc[i][p] = 0.0f;
            conv_chunk<2>(sx, sw, dhg, w0, acc);
            const float* ap = sa + t * NW + w0;
            #pragma unroll
            for (int p = 0; p < 8; ++p) {
                float a = ap[p];
                pacc[0][p] += a * acc[0][p];
                pacc[1][p] += a * acc[1][p];
            }
        }
    }
    #pragma unroll
    for (int i = 0; i < 2; ++i) {
        int oc = half * 64 + dhg + 32 * i;
        #pragma unroll
        for (int p = 0; p < 8; ++p)
            pooled[((size_t)b * NDH + oc) * HWs + h * NW + w0 + p] = pacc[i][p];
    }
}

// ---------------- K5: out = conv(pooled, w_out) + b_out, broadcast over T --------
__global__ __launch_bounds__(256) void conv_out_kernel(const float* __restrict__ pooled,
        const float* __restrict__ w_out, const float* __restrict__ b_out,
        float* __restrict__ out) {
    __shared__ float sx[CCH * 3 * XSW];
    __shared__ float sw[128 * SWP];
    int blk = blockIdx.x;                 // ((b*64)+h)*2 + half
    int half = blk & 1;
    int h = (blk >> 1) & 63;
    int b = blk >> 7;
    int tid = threadIdx.x;
    int dhg = tid & 31, wg = tid >> 5;
    int w0 = wg * 8;
    const float* frame = pooled + (size_t)b * NDH * HWs;
    float acc[4][8];
    #pragma unroll
    for (int i = 0; i < 4; ++i)
        #pragma unroll
        for (int p = 0; p < 8; ++p) acc[i][p] = 0.0f;
    for (int c0 = 0; c0 < NDH; c0 += CCH) {
        __syncthreads();
        stage_x(frame + (size_t)c0 * HWs, h, sx, tid);
        stage_w<128>(w_out + ((size_t)(half * 128) * NDH + c0) * 9, NDH * 9, sw, tid);
        __syncthreads();
        conv_chunk<4>(sx, sw, dhg, w0, acc);
    }
    #pragma unroll
    for (int i = 0; i < 4; ++i) {
        int oc = half * 128 + dhg + 32 * i;
        float bias = b_out[oc];
        #pragma unroll
        for (int p = 0; p < 8; ++p) {
            float val = acc[i][p] + bias;
            #pragma unroll
            for (int t = 0; t < NT; ++t)
                out[(((size_t)(b * NT + t)) * NC + oc) * HWs + h * NW + w0 + p] = val;
        }
    }
}

extern "C" void kernel_launch(void* const* d_in, const int* in_sizes, int n_in,
                              void* d_out, int out_size, void* d_ws, size_t ws_size,
                              hipStream_t stream) {
    const float* x     = (const float*)d_in[0];
    const float* w_k   = (const float*)d_in[1];
    const float* w_q   = (const float*)d_in[2];
    const float* w_v   = (const float*)d_in[3];
    const float* w_out = (const float*)d_in[4];
    const float* b_out = (const float*)d_in[5];
    float* out = (float*)d_out;

    float* kbuf   = (float*)d_ws;                       // NB*NDH*HWs = 2,097,152 f
    float* dots   = kbuf + (size_t)NB * NDH * HWs;      // NB*NT*HWs  =   131,072 f
    float* pooled = dots + (size_t)NB * NT * HWs;       // NB*NDH*HWs = 2,097,152 f

    hipLaunchKernelGGL(conv_k_kernel,      dim3(NB * NH * 2),  dim3(256), 0, stream, x, w_k, kbuf);
    hipLaunchKernelGGL(conv_q_dots_kernel, dim3(NB * NT * NH), dim3(256), 0, stream, x, w_q, kbuf, dots);
    hipLaunchKernelGGL(softmax_t_kernel,   dim3(64),           dim3(256), 0, stream, dots);
    hipLaunchKernelGGL(conv_v_pool_kernel, dim3(NB * NH * 2),  dim3(256), 0, stream, x, w_v, dots, pooled);
    hipLaunchKernelGGL(conv_out_kernel,    dim3(NB * NH * 2),  dim3(256), 0, stream, pooled, w_out, b_out, out);
}

// Round 3
// 554.006 us; speedup vs baseline: 38.1386x; 8.6214x over previous
//
#include <hip/hip_runtime.h>
#include <cstdint>
#include <cstddef>

#define NB 4
#define NT 8
#define NC 256
#define NDH 128
#define HWs 4096

typedef _Float16 f16;
typedef _Float16 f16x8 __attribute__((ext_vector_type(8)));
typedef float f32x16 __attribute__((ext_vector_type(16)));

// ============================================================================
// Workspace layout (bytes):
//  xh      @ 0          : 32*64*64*256 f16  = 67,108,864   x transposed [bt][h][w][c]
//  kbuf    @ 67108864   : 4*128*4096 f32    =  8,388,608   k NCHW
//  dots    @ 75497472   : 4*8*4096 f32      =    524,288   logits/attn
//  parts   @ 76021760   : 8*4*128*4096 f16  = 33,554,432   per-t weighted v, NCHW
//  pooledT @ 109576192  : 4*64*64*128 f16   =  4,194,304   pooled transposed [b][h][w][dh]
//  wq2     @ 113770496  : 589,824           weights [tap][cg][oc][8c] f16
//  wk2     @ 114360320  : 589,824
//  wv2     @ 114950144  : 589,824
//  wo2     @ 115539968  : 589,824
//  total ≈ 110.8 MiB
// ============================================================================

// ---------------- prep: x (B,T,C,H,W) f32 -> xh [bt][h][w][c] f16 ------------
__global__ __launch_bounds__(256) void prep_x_kernel(const float* __restrict__ x,
                                                     f16* __restrict__ xh) {
    __shared__ f16 sxt[256 * 66];          // [c][w], stride 66 breaks bank conflicts
    int bt = blockIdx.x >> 6, h = blockIdx.x & 63;
    int tid = threadIdx.x;
    int w = tid & 63, c4 = tid >> 6;
    for (int p = 0; p < 64; ++p) {
        int c = p * 4 + c4;
        sxt[c * 66 + w] = (f16)x[(((size_t)bt * NC + c) * 64 + h) * 64 + w];
    }
    __syncthreads();
    int cg = tid & 31, wb = tid >> 5;      // wb 0..7
    f16x8* xh8 = (f16x8*)xh;
    for (int p = 0; p < 8; ++p) {
        int w2 = wb * 8 + p;
        f16x8 v;
        #pragma unroll
        for (int j = 0; j < 8; ++j) v[j] = sxt[(cg * 8 + j) * 66 + w2];
        xh8[((size_t)(bt * 64 + h) * 64 + w2) * 32 + cg] = v;
    }
}

// ---------------- prep: weights (OC,CIN,3,3) f32 -> [tap][cg][oc][8] f16 -----
__global__ __launch_bounds__(256) void prep_w_kernel(const float* __restrict__ w,
                                                     f16* __restrict__ wt2,
                                                     int OC, int CIN) {
    int CG = CIN >> 3;
    int idx = blockIdx.x * 256 + threadIdx.x;
    if (idx >= OC * CG) return;
    int oc = idx / CG, cg = idx - oc * CG;
    f16x8* wt8 = (f16x8*)wt2;
    #pragma unroll
    for (int tap = 0; tap < 9; ++tap) {
        f16x8 v;
        #pragma unroll
        for (int j = 0; j < 8; ++j)
            v[j] = (f16)w[((size_t)oc * CIN + cg * 8 + j) * 9 + tap];
        wt8[((size_t)tap * CG + cg) * OC + oc] = v;
    }
}

// ============================================================================
// conv core: implicit-GEMM 3x3 conv via mfma_f32_32x32x16_f16.
// Block: 128 oc x 4 output rows x 64 cols. Wave wv = row wv; a=4 oc-tiles,
// b=2 col-tiles; acc[4][2] f32x16.
// LDS x stage: [r 0..5][cidx 0..65][s 0..1] f16x8; slot s holds channel group
//   cg0 + (s ^ ((cidx>>2)&1))   (swizzle -> conflict-free B-frag reads)
// LDS w stage: [tap][q][128 oc] f16x8 (contiguous -> conflict-free A-frag reads)
// Fragment maps (gfx950): A[m=lane&31][k=8*(lane>>5)+j], B[k=8*(lane>>5)+j][n=lane&31],
// D: col=lane&31, row=(reg&3)+8*(reg>>2)+4*(lane>>5).
// ============================================================================
template <int CIN>
__device__ __forceinline__ void conv_core(const f16x8* __restrict__ xh8,  // frame base
                                          const f16x8* __restrict__ wt8,
                                          int OCT, int oc0, int h0,
                                          f16x8* __restrict__ sx8,
                                          f16x8* __restrict__ sw8,
                                          f32x16 acc[4][2]) {
    const int tid = threadIdx.x;
    const int lane = tid & 63;
    const int wv = tid >> 6;
    const int n = lane & 31, q = lane >> 5;
    const int CG = CIN / 8;

    #pragma unroll
    for (int i = 0; i < 4; ++i)
        #pragma unroll
        for (int ct = 0; ct < 2; ++ct)
            #pragma unroll
            for (int r = 0; r < 16; ++r) acc[i][ct][r] = 0.0f;

    f16x8 Z8 = {(f16)0, (f16)0, (f16)0, (f16)0, (f16)0, (f16)0, (f16)0, (f16)0};

    for (int c0 = 0; c0 < CIN; c0 += 16) {
        const int cg0 = c0 >> 3;
        __syncthreads();
        // ---- stage weights: 36 jobs (tap, qh, half), 9 per wave
        for (int j = wv; j < 36; j += 4) {
            int tap = j >> 2, qh = (j >> 1) & 1, hf = j & 1;
            int oc = hf * 64 + lane;
            sw8[(tap * 2 + qh) * 128 + oc] =
                wt8[(size_t)(tap * CG + cg0 + qh) * OCT + oc0 + oc];
        }
        // ---- stage x rows r = wv, wv+4
        for (int r = wv; r < 6; r += 4) {
            int h = h0 - 1 + r;
            if ((unsigned)h < 64u) {
                #pragma unroll
                for (int cb = 0; cb < 2; ++cb) {
                    int col = cb * 32 + (lane >> 1);
                    int sl = lane & 1;
                    int cidx = col + 1;
                    int cg = cg0 + (sl ^ ((cidx >> 2) & 1));
                    sx8[r * 132 + cidx * 2 + sl] = xh8[(size_t)(h * 64 + col) * CG + cg];
                }
                if (lane < 4)   // zero halo cols cidx=0,65
                    sx8[r * 132 + (lane >> 1) * 130 + (lane & 1)] = Z8;
            } else {            // out-of-range row: all zero (132 slots)
                sx8[r * 132 + lane] = Z8;
                sx8[r * 132 + 64 + lane] = Z8;
                if (lane < 4) sx8[r * 132 + 128 + lane] = Z8;
            }
        }
        __syncthreads();
        // ---- compute
        #pragma unroll
        for (int tap = 0; tap < 9; ++tap) {
            const int ky = tap / 3, kx = tap % 3;
            f16x8 a[4];
            #pragma unroll
            for (int i = 0; i < 4; ++i)
                a[i] = sw8[(tap * 2 + q) * 128 + 32 * i + n];
            #pragma unroll
            for (int ct = 0; ct < 2; ++ct) {
                int cidx = ct * 32 + n + kx;
                int s = q ^ ((cidx >> 2) & 1);
                f16x8 b = sx8[(wv + ky) * 132 + cidx * 2 + s];
                #pragma unroll
                for (int i = 0; i < 4; ++i)
                    acc[i][ct] = __builtin_amdgcn_mfma_f32_32x32x16_f16(a[i], b, acc[i][ct], 0, 0, 0);
            }
        }
    }
}

// ---------------- K1: k = conv(x[:,0], w_k) -> kbuf NCHW f32 -----------------
__global__ __launch_bounds__(256, 2) void conv_k_kernel(const f16* __restrict__ xh,
        const f16* __restrict__ wk2, float* __restrict__ kbuf) {
    __shared__ f16x8 sx8[6 * 132];
    __shared__ f16x8 sw8[9 * 2 * 128];
    int b = blockIdx.x >> 4, hb = blockIdx.x & 15;
    int h0 = hb * 4;
    int bt = b * NT;   // t = 0
    f32x16 acc[4][2];
    conv_core<NC>((const f16x8*)xh + (size_t)bt * 64 * 64 * 32, (const f16x8*)wk2,
                  NDH, 0, h0, sx8, sw8, acc);
    int lane = threadIdx.x & 63, wv = threadIdx.x >> 6;
    int n = lane & 31, q = lane >> 5;
    int h = h0 + wv;
    #pragma unroll
    for (int i = 0; i < 4; ++i)
        #pragma unroll
        for (int r = 0; r < 16; ++r) {
            int oc = 32 * i + 4 * q + (r & 3) + 8 * (r >> 2);
            float* kp = kbuf + ((size_t)(b * NDH + oc)) * HWs + h * 64;
            kp[n] = acc[i][0][r];
            kp[32 + n] = acc[i][1][r];
        }
}

// ---------------- K2: dots = sum_dh conv_q(x[bt]) * k ------------------------
__global__ __launch_bounds__(256, 2) void conv_q_kernel(const f16* __restrict__ xh,
        const f16* __restrict__ wq2, const float* __restrict__ kbuf,
        float* __restrict__ dots) {
    __shared__ f16x8 sx8[6 * 132];
    __shared__ f16x8 sw8[9 * 2 * 128];
    int bt = blockIdx.x >> 4, hb = blockIdx.x & 15;
    int b = bt >> 3;
    int h0 = hb * 4;
    f32x16 acc[4][2];
    conv_core<NC>((const f16x8*)xh + (size_t)bt * 64 * 64 * 32, (const f16x8*)wq2,
                  NDH, 0, h0, sx8, sw8, acc);
    int lane = threadIdx.x & 63, wv = threadIdx.x >> 6;
    int n = lane & 31, q = lane >> 5;
    int h = h0 + wv;
    float p0 = 0.0f, p1 = 0.0f;
    #pragma unroll
    for (int i = 0; i < 4; ++i)
        #pragma unroll
        for (int r = 0; r < 16; ++r) {
            int oc = 32 * i + 4 * q + (r & 3) + 8 * (r >> 2);
            const float* kp = kbuf + ((size_t)(b * NDH + oc)) * HWs + h * 64;
            p0 += acc[i][0][r] * kp[n];
            p1 += acc[i][1][r] * kp[32 + n];
        }
    p0 += __shfl_xor(p0, 32, 64);
    p1 += __shfl_xor(p1, 32, 64);
    if (q == 0) {
        dots[(size_t)bt * HWs + h * 64 + n] = p0;
        dots[(size_t)bt * HWs + h * 64 + 32 + n] = p1;
    }
}

// ---------------- K3: softmax over T (in place) ------------------------------
__global__ __launch_bounds__(256) void softmax_t_kernel(float* __restrict__ dots) {
    int idx = blockIdx.x * 256 + threadIdx.x;   // NB*HWs = 16384
    int b = idx >> 12;
    int p = idx & 4095;
    float* base = dots + (size_t)b * NT * HWs + p;
    float v[NT];
    float m = -3.4e38f;
    #pragma unroll
    for (int t = 0; t < NT; ++t) { v[t] = base[t * HWs]; m = fmaxf(m, v[t]); }
    float s = 0.0f;
    #pragma unroll
    for (int t = 0; t < NT; ++t) { v[t] = __expf(v[t] - m); s += v[t]; }
    float inv = 1.0f / s;
    #pragma unroll
    for (int t = 0; t < NT; ++t) base[t * HWs] = v[t] * inv;
}

// ---------------- K4: parts[t] = attn[t] * conv_v(x[b,t])  (f16 NCHW) --------
__global__ __launch_bounds__(256, 2) void conv_v_kernel(const f16* __restrict__ xh,
        const f16* __restrict__ wv2, const float* __restrict__ attn,
        f16* __restrict__ parts) {
    __shared__ f16x8 sx8[6 * 132];
    __shared__ f16x8 sw8[9 * 2 * 128];
    int bt = blockIdx.x >> 4, hb = blockIdx.x & 15;
    int b = bt >> 3, t = bt & 7;
    int h0 = hb * 4;
    f32x16 acc[4][2];
    conv_core<NC>((const f16x8*)xh + (size_t)bt * 64 * 64 * 32, (const f16x8*)wv2,
                  NDH, 0, h0, sx8, sw8, acc);
    int lane = threadIdx.x & 63, wv = threadIdx.x >> 6;
    int n = lane & 31, q = lane >> 5;
    int h = h0 + wv;
    float a0 = attn[(size_t)bt * HWs + h * 64 + n];
    float a1 = attn[(size_t)bt * HWs + h * 64 + 32 + n];
    f16* pp = parts + (size_t)(t * NB + b) * NDH * HWs;
    #pragma unroll
    for (int i = 0; i < 4; ++i)
        #pragma unroll
        for (int r = 0; r < 16; ++r) {
            int oc = 32 * i + 4 * q + (r & 3) + 8 * (r >> 2);
            f16* op = pp + (size_t)oc * HWs + h * 64;
            op[n] = (f16)(a0 * acc[i][0][r]);
            op[32 + n] = (f16)(a1 * acc[i][1][r]);
        }
}

// ---------------- prep: pooled = sum_t parts -> pooledT [b][h][w][dh] f16 ----
__global__ __launch_bounds__(256) void prep_pooled_kernel(const f16* __restrict__ parts,
                                                          f16* __restrict__ pooledT) {
    __shared__ f16 sxt[128 * 66];
    int b = blockIdx.x >> 6, h = blockIdx.x & 63;
    int tid = threadIdx.x, w = tid & 63, c4 = tid >> 6;
    for (int p = 0; p < 32; ++p) {
        int c = p * 4 + c4;
        float s = 0.0f;
        #pragma unroll
        for (int t = 0; t < NT; ++t)
            s += (float)parts[(((size_t)(t * NB + b) * NDH + c)) * HWs + h * 64 + w];
        sxt[c * 66 + w] = (f16)s;
    }
    __syncthreads();
    int cg = tid & 15, wb = tid >> 4;  // wb 0..15
    f16x8* pt8 = (f16x8*)pooledT;
    for (int p = 0; p < 4; ++p) {
        int w2 = wb * 4 + p;
        f16x8 v;
        #pragma unroll
        for (int j = 0; j < 8; ++j) v[j] = sxt[(cg * 8 + j) * 66 + w2];
        pt8[((size_t)(b * 64 + h) * 64 + w2) * 16 + cg] = v;
    }
}

// ---------------- K5: out = conv(pooled, w_out) + bias, broadcast over T -----
__global__ __launch_bounds__(256, 2) void conv_out_kernel(const f16* __restrict__ pooledT,
        const f16* __restrict__ wo2, const float* __restrict__ b_out,
        float* __restrict__ out) {
    __shared__ f16x8 sx8[6 * 132];
    __shared__ f16x8 sw8[9 * 2 * 128];
    int b = blockIdx.x >> 5, oh = (blockIdx.x >> 4) & 1, hb = blockIdx.x & 15;
    int h0 = hb * 4;
    f32x16 acc[4][2];
    conv_core<NDH>((const f16x8*)pooledT + (size_t)b * 64 * 64 * 16, (const f16x8*)wo2,
                   NC, oh * 128, h0, sx8, sw8, acc);
    int lane = threadIdx.x & 63, wv = threadIdx.x >> 6;
    int n = lane & 31, q = lane >> 5;
    int h = h0 + wv;
    #pragma unroll
    for (int i = 0; i < 4; ++i)
        #pragma unroll
        for (int r = 0; r < 16; ++r) {
            int oc = oh * 128 + 32 * i + 4 * q + (r & 3) + 8 * (r >> 2);
            float bias = b_out[oc];
            float v0 = acc[i][0][r] + bias;
            float v1 = acc[i][1][r] + bias;
            for (int t = 0; t < NT; ++t) {
                float* op = out + ((size_t)(b * NT + t) * NC + oc) * HWs + h * 64;
                op[n] = v0;
                op[32 + n] = v1;
            }
        }
}

// ============================================================================
extern "C" void kernel_launch(void* const* d_in, const int* in_sizes, int n_in,
                              void* d_out, int out_size, void* d_ws, size_t ws_size,
                              hipStream_t stream) {
    (void)in_sizes; (void)n_in; (void)out_size; (void)ws_size;
    const float* x     = (const float*)d_in[0];
    const float* w_k   = (const float*)d_in[1];
    const float* w_q   = (const float*)d_in[2];
    const float* w_v   = (const float*)d_in[3];
    const float* w_out = (const float*)d_in[4];
    const float* b_out = (const float*)d_in[5];
    float* out = (float*)d_out;

    char* ws = (char*)d_ws;
    f16*   xh      = (f16*)ws;
    float* kbuf    = (float*)(ws + 67108864);
    float* dots    = (float*)(ws + 75497472);
    f16*   parts   = (f16*)(ws + 76021760);
    f16*   pooledT = (f16*)(ws + 109576192);
    f16*   wq2     = (f16*)(ws + 113770496);
    f16*   wk2     = (f16*)(ws + 114360320);
    f16*   wv2     = (f16*)(ws + 114950144);
    f16*   wo2     = (f16*)(ws + 115539968);

    hipLaunchKernelGGL(prep_x_kernel, dim3(2048), dim3(256), 0, stream, x, xh);
    hipLaunchKernelGGL(prep_w_kernel, dim3(16), dim3(256), 0, stream, w_q, wq2, NDH, NC);
    hipLaunchKernelGGL(prep_w_kernel, dim3(16), dim3(256), 0, stream, w_k, wk2, NDH, NC);
    hipLaunchKernelGGL(prep_w_kernel, dim3(16), dim3(256), 0, stream, w_v, wv2, NDH, NC);
    hipLaunchKernelGGL(prep_w_kernel, dim3(16), dim3(256), 0, stream, w_out, wo2, NC, NDH);

    hipLaunchKernelGGL(conv_k_kernel, dim3(NB * 16), dim3(256), 0, stream, xh, wk2, kbuf);
    hipLaunchKernelGGL(conv_q_kernel, dim3(NB * NT * 16), dim3(256), 0, stream, xh, wq2, kbuf, dots);
    hipLaunchKernelGGL(softmax_t_kernel, dim3(64), dim3(256), 0, stream, dots);
    hipLaunchKernelGGL(conv_v_kernel, dim3(NB * NT * 16), dim3(256), 0, stream, xh, wv2, dots, parts);
    hipLaunchKernelGGL(prep_pooled_kernel, dim3(256), dim3(256), 0, stream, parts, pooledT);
    hipLaunchKernelGGL(conv_out_kernel, dim3(NB * 16 * 2), dim3(256), 0, stream, pooledT, wo2, b_out, out);
}